// Round 4
// baseline (91654.730 us; speedup 1.0000x reference)
//
#include <hip/hip_runtime.h>
#include <hip/hip_fp16.h>

// RecurrentQNet: B=64, S=1024, D=64, H=512, A=16
// R5: fence-free slice-parallel persistent recurrence.
//   R4 post-mortem: agent acquire/release FENCES at every grid barrier lowered
//   to buffer_inv/buffer_wbl2 -> L1/L2 invalidated 3072 times -> weight slices
//   refetched every step (FETCH 40GB, 13MB/barrier) -> 110ms.
//   R5: ALL cross-WG exchange (h/u/pred/flags) via RELAXED agent-scope atomics
//   (sc0/sc1 bypass ops, no cache maintenance). Release ordering = the vmcnt(0)
//   drain __syncthreads() already performs before s_barrier; acquire unneeded
//   since sc1 loads bypass stale caches. Flags packed at 4B stride (512B).
//   Numerics identical to R4 (passed at 1.95e-3): f16 chains of 16 products,
//   fp32 u exchange, fp32 pred path.

#define B_ 64
#define S_ 1024
#define D_ 64
#define H_ 512
#define A_ 16

// ---- workspace layout in uint4 units ----
#define OFF_WGX   0          // [128][12][4][16] u4 : W_hh slices f16
#define OFF_WGI   98304      // [128][12][4][4]  u4 : W_ih slices f16
#define OFF_WUX   122880     // [128][4][4][16]  u4 : cb_w1 slices f16
#define OFF_SYNC  155648     // flags[128] packed 4B; dead at uint idx 160
#define OFF_H2    155712     // [2][64][64] u4 : h exchange f16, parity-buffered
#define OFF_U2    163904     // [64][512] f32 : u exchange (8192 u4)
#define OFF_PRED2 172096     // [64][32] uint : pred exchange f16 (512 u4)
#define WS_TOTAL  172608

#define NWG 128

typedef unsigned long long ull;

union V16 {
    uint4   u;
    float4  f;
    __half2 h[4];
    ull     u64[2];
};
union V8 {
    ull     u;
    float2  f;
    __half2 h2v[2];
    unsigned w[2];
};

__device__ __forceinline__ ull aload8(const ull* p) {
    return __hip_atomic_load(p, __ATOMIC_RELAXED, __HIP_MEMORY_SCOPE_AGENT);
}
__device__ __forceinline__ void astore8(ull* p, ull v) {
    __hip_atomic_store(p, v, __ATOMIC_RELAXED, __HIP_MEMORY_SCOPE_AGENT);
}
__device__ __forceinline__ unsigned aload4(const unsigned* p) {
    return __hip_atomic_load(p, __ATOMIC_RELAXED, __HIP_MEMORY_SCOPE_AGENT);
}
__device__ __forceinline__ void astore4(unsigned* p, unsigned v) {
    __hip_atomic_store(p, v, __ATOMIC_RELAXED, __HIP_MEMORY_SCOPE_AGENT);
}

// ---------------- K0: one-time weight convert + zero sync/exchange ----------------
__global__ __launch_bounds__(256) void k_convert(
    const float* __restrict__ W_ih,   // [1536,128]
    const float* __restrict__ W_hh,   // [1536,512]
    const float* __restrict__ cb_w1,  // [512,512]
    uint4* __restrict__ ws)
{
    int idx = blockIdx.x * 256 + threadIdx.x;
    const float* src;
    if (idx < OFF_WGI) {                         // W_hh: [wg][r=g*4+jj][c][q]
        int wg = idx / 768, rem = idx % 768;
        int r = rem >> 6, c = (rem >> 4) & 3, q = rem & 15;
        int g = r >> 2, jj = r & 3;
        src = W_hh + (size_t)(g * 512 + wg * 4 + jj) * 512 + c * 128 + q * 8;
    } else if (idx < OFF_WUX) {                  // W_ih: [wg][r][c][q2]
        int i2 = idx - OFF_WGI;
        int wg = i2 / 192, rem = i2 % 192;
        int r = rem >> 4, c = (rem >> 2) & 3, q2 = rem & 3;
        int g = r >> 2, jj = r & 3;
        src = W_ih + (size_t)(g * 512 + wg * 4 + jj) * 128 + c * 32 + q2 * 8;
    } else if (idx < OFF_SYNC) {                 // cb_w1: [wg][jr][c][q]
        int i2 = idx - OFF_WUX;
        int wg = i2 / 256, rem = i2 % 256;
        int jr = rem >> 6, c = (rem >> 4) & 3, q = rem & 15;
        src = cb_w1 + (size_t)(wg * 4 + jr) * 512 + c * 128 + q * 8;
    } else if (idx < WS_TOTAL) {                 // zero sync + h2 + u2 + pred2
        ws[idx] = make_uint4(0u, 0u, 0u, 0u);
        return;
    } else return;
    V16 o;
#pragma unroll
    for (int i = 0; i < 4; ++i) o.h[i] = __floats2half2_rn(src[2 * i], src[2 * i + 1]);
    ws[idx] = o.u;
}

// ---------------- fence-free flat grid barrier ----------------
__device__ __forceinline__ int poll_ge(unsigned* p, unsigned bn, unsigned* dead) {
    unsigned it = 0;
    while (aload4(p) < bn) {
        __builtin_amdgcn_s_sleep(1);
        if ((++it & 2047u) == 0u) {
            if (aload4(dead) != 0u) return 1;
            if (it > (1u << 24)) {   // ~1s: residency failure -> bail, don't hang
                astore4(dead, 1u);
                return 1;
            }
        }
    }
    return 0;
}

__device__ __forceinline__ int gbar(unsigned* flags, unsigned* dead, unsigned bn,
                                    unsigned* s_flag) {
    const int tid = threadIdx.x;
    __syncthreads();         // drains vmcnt(0): all this WG's sc1 stores visible
    if (tid == 0) {
        *s_flag = 0u;
        astore4(flags + blockIdx.x, bn);
    }
    if (tid < NWG) {
        if (poll_ge(flags + tid, bn, dead)) *s_flag = 1u;
    }
    __syncthreads();         // polls done; s_flag visible
    return *s_flag != 0u;
}

// ---------------- K1: slice-parallel recurrence ----------------
// thread tid: b = tid>>2 (batch), c = tid&3 (K-quarter). WG wg: j-slice 4wg..4wg+3.
__global__ __launch_bounds__(256) void k_recur(
    const uint4* __restrict__ wsb,
    unsigned* __restrict__ syncw,      // flags packed; dead at +160
    uint4* __restrict__ h2u4,          // [2][64][64] u4
    float* __restrict__ u2f,           // [64][512] f32
    unsigned* __restrict__ pred2w,     // [64][32] uint (f16 pairs)
    const float* __restrict__ x,       // [64,1024,64] fp32
    const float* __restrict__ b_ih, const float* __restrict__ b_hh,
    const float* __restrict__ cb_b1, const float* __restrict__ cb_b2,
    const float* __restrict__ cb_w2,   // [64,512] fp32
    float* __restrict__ hist,          // [64,1024,512]
    float* __restrict__ hidden,        // [64,512]
    float* __restrict__ cbp)           // [64,1024,64]
{
    __shared__ unsigned s_flag;
    const int tid = threadIdx.x;
    const int wg = blockIdx.x;
    const int b = tid >> 2;
    const int c = tid & 3;
    const int j4 = wg * 4;

    unsigned* dead = syncw + 160;

    const uint4* wgxP = wsb + OFF_WGX + wg * 768 + c * 16;   // [r*64 + q]
    const uint4* wgiP = wsb + OFF_WGI + wg * 192 + c * 4;    // [r*16 + q2]
    const uint4* wuxP = wsb + OFF_WUX + wg * 256 + c * 16;   // [r*64 + q]

    float bias_r[4], bias_z[4], bias_ni[4], bias_nh[4], bias_u[4];
#pragma unroll
    for (int jj = 0; jj < 4; ++jj) {
        int j = j4 + jj;
        bias_r[jj]  = b_ih[j] + b_hh[j];
        bias_z[jj]  = b_ih[512 + j] + b_hh[512 + j];
        bias_ni[jj] = b_ih[1024 + j];
        bias_nh[jj] = b_hh[1024 + j];
        bias_u[jj]  = cb_b1[j];
    }
    const int dl = tid >> 3, oct = tid & 7;
    const int pb = wg >> 1, d = (wg & 1) * 32 + dl;
    const float bias_p = cb_b2[d];

    float hprev[4] = {0.f, 0.f, 0.f, 0.f};

    ull* h2base = (ull*)h2u4;                    // parity stride 8192 ull

    unsigned bn = 0;

    for (int t = 0; t < S_; ++t) {
        const int par = t & 1;
        const ull* hPrv = h2base + (size_t)(1 - par) * 8192 + b * 128 + c * 32; // h_{t-1}
        const ull* hCur = h2base + (size_t)par * 8192 + b * 128 + c * 32;       // h_t

        // ======== phase 1: gates (f16 chains of 16 products, f32 flush) ========
        float accf[16];
#pragma unroll
        for (int i = 0; i < 16; ++i) accf[i] = 0.f;
        {
#pragma unroll
            for (int grp = 0; grp < 8; ++grp) {      // hh part: 2 uint4 per flush
                __half2 ha[12];
#pragma unroll
                for (int r = 0; r < 12; ++r) ha[r] = __float2half2_rn(0.f);
#pragma unroll
                for (int qq = 0; qq < 2; ++qq) {
                    const int q = grp * 2 + qq;
                    V16 a;
                    a.u64[0] = aload8(hPrv + q * 2);
                    a.u64[1] = aload8(hPrv + q * 2 + 1);
#pragma unroll
                    for (int r = 0; r < 12; ++r) {
                        V16 w; w.u = wgxP[r * 64 + q];
                        ha[r] = __hfma2(w.h[0], a.h[0], ha[r]);
                        ha[r] = __hfma2(w.h[1], a.h[1], ha[r]);
                        ha[r] = __hfma2(w.h[2], a.h[2], ha[r]);
                        ha[r] = __hfma2(w.h[3], a.h[3], ha[r]);
                    }
                }
#pragma unroll
                for (int r = 0; r < 12; ++r) {
                    float2 f = __half22float2(ha[r]);
                    accf[r] += f.x + f.y;
                }
            }
            // gi part: K=128 over [x_t | pred_{t-1}]; n-gate gi -> accf[12..15]
            V16 a4[4];
            if (c < 2) {
                const float4* xp = (const float4*)(x + ((size_t)b * S_ + t) * D_ + c * 32);
#pragma unroll
                for (int q2 = 0; q2 < 4; ++q2) {
                    float4 f0 = xp[q2 * 2], f1 = xp[q2 * 2 + 1];
                    a4[q2].h[0] = __floats2half2_rn(f0.x, f0.y);
                    a4[q2].h[1] = __floats2half2_rn(f0.z, f0.w);
                    a4[q2].h[2] = __floats2half2_rn(f1.x, f1.y);
                    a4[q2].h[3] = __floats2half2_rn(f1.z, f1.w);
                }
            } else {
                const ull* pp = (const ull*)(pred2w + b * 32 + (c - 2) * 16);
#pragma unroll
                for (int q2 = 0; q2 < 4; ++q2) {
                    a4[q2].u64[0] = aload8(pp + q2 * 2);
                    a4[q2].u64[1] = aload8(pp + q2 * 2 + 1);
                }
            }
#pragma unroll
            for (int g2 = 0; g2 < 2; ++g2) {
                __half2 hb[12];
#pragma unroll
                for (int r = 0; r < 12; ++r) hb[r] = __float2half2_rn(0.f);
#pragma unroll
                for (int qq = 0; qq < 2; ++qq) {
                    const int q2 = g2 * 2 + qq;
                    V16 a = a4[q2];
#pragma unroll
                    for (int r = 0; r < 12; ++r) {
                        V16 w; w.u = wgiP[r * 16 + q2];
                        hb[r] = __hfma2(w.h[0], a.h[0], hb[r]);
                        hb[r] = __hfma2(w.h[1], a.h[1], hb[r]);
                        hb[r] = __hfma2(w.h[2], a.h[2], hb[r]);
                        hb[r] = __hfma2(w.h[3], a.h[3], hb[r]);
                    }
                }
#pragma unroll
                for (int r = 0; r < 12; ++r) {
                    float2 f = __half22float2(hb[r]);
                    float v = f.x + f.y;
                    if (r < 8) accf[r] += v;
                    else       accf[12 + (r - 8)] += v;
                }
            }
        }
#pragma unroll
        for (int i = 0; i < 16; ++i) {
            accf[i] += __shfl_xor(accf[i], 1);
            accf[i] += __shfl_xor(accf[i], 2);
        }
        if (c == 0) {
            float h[4];
#pragma unroll
            for (int jj = 0; jj < 4; ++jj) {
                float rr = 1.f / (1.f + __expf(-(accf[jj] + bias_r[jj])));
                float zz = 1.f / (1.f + __expf(-(accf[4 + jj] + bias_z[jj])));
                float nn = tanhf(accf[12 + jj] + bias_ni[jj] + rr * (accf[8 + jj] + bias_nh[jj]));
                h[jj] = (1.f - zz) * nn + zz * hprev[jj];
                hprev[jj] = h[jj];
            }
            *(float4*)(hist + ((size_t)b * S_ + t) * H_ + j4) = make_float4(h[0], h[1], h[2], h[3]);
            if (t == S_ - 1)
                *(float4*)(hidden + (size_t)b * H_ + j4) = make_float4(h[0], h[1], h[2], h[3]);
            V8 pk;
            pk.h2v[0] = __floats2half2_rn(h[0], h[1]);
            pk.h2v[1] = __floats2half2_rn(h[2], h[3]);
            astore8(h2base + (size_t)par * 8192 + b * 128 + wg, pk.u);
        }
        ++bn; if (gbar(syncw, dead, bn, &s_flag)) return;

        // ======== phase 2: u = relu(cb_w1 @ h_t + b1), u kept fp32 ========
        {
            float uacc[4] = {0.f, 0.f, 0.f, 0.f};
#pragma unroll
            for (int grp = 0; grp < 8; ++grp) {
                __half2 ha[4];
#pragma unroll
                for (int r = 0; r < 4; ++r) ha[r] = __float2half2_rn(0.f);
#pragma unroll
                for (int qq = 0; qq < 2; ++qq) {
                    const int q = grp * 2 + qq;
                    V16 a;
                    a.u64[0] = aload8(hCur + q * 2);
                    a.u64[1] = aload8(hCur + q * 2 + 1);
#pragma unroll
                    for (int r = 0; r < 4; ++r) {
                        V16 w; w.u = wuxP[r * 64 + q];
                        ha[r] = __hfma2(w.h[0], a.h[0], ha[r]);
                        ha[r] = __hfma2(w.h[1], a.h[1], ha[r]);
                        ha[r] = __hfma2(w.h[2], a.h[2], ha[r]);
                        ha[r] = __hfma2(w.h[3], a.h[3], ha[r]);
                    }
                }
#pragma unroll
                for (int r = 0; r < 4; ++r) { float2 f = __half22float2(ha[r]); uacc[r] += f.x + f.y; }
            }
#pragma unroll
            for (int r = 0; r < 4; ++r) {
                uacc[r] += __shfl_xor(uacc[r], 1);
                uacc[r] += __shfl_xor(uacc[r], 2);
            }
            if (c == 0) {
                V8 p0, p1;
                p0.f = make_float2(fmaxf(uacc[0] + bias_u[0], 0.f),
                                   fmaxf(uacc[1] + bias_u[1], 0.f));
                p1.f = make_float2(fmaxf(uacc[2] + bias_u[2], 0.f),
                                   fmaxf(uacc[3] + bias_u[3], 0.f));
                astore8((ull*)u2f + (size_t)b * 256 + wg * 2, p0.u);
                astore8((ull*)u2f + (size_t)b * 256 + wg * 2 + 1, p1.u);
            }
        }
        ++bn; if (gbar(syncw, dead, bn, &s_flag)) return;

        // ======== phase 3: pred = cb_w2 @ u + b2, fully fp32 ========
        {
            float pacc = 0.f;
            const ull* uvp = (const ull*)u2f + (size_t)pb * 256 + oct * 32;
            const float4* wv = (const float4*)(cb_w2 + (size_t)d * 512 + oct * 64);
#pragma unroll
            for (int i = 0; i < 16; ++i) {
                V8 a0, a1;
                a0.u = aload8(uvp + i * 2);
                a1.u = aload8(uvp + i * 2 + 1);
                float4 w = wv[i];
                pacc += a0.f.x * w.x + a0.f.y * w.y + a1.f.x * w.z + a1.f.y * w.w;
            }
            pacc += __shfl_xor(pacc, 1);
            pacc += __shfl_xor(pacc, 2);
            pacc += __shfl_xor(pacc, 4);
            float pv = pacc + bias_p;
            if (oct == 0) cbp[((size_t)pb * S_ + t) * 64 + d] = pv;
            float po = __shfl_down(pv, 8);          // pred of d+1 (same wave)
            if ((tid & 15) == 0) {
                __half2 ph = __floats2half2_rn(pv, po);
                astore4(pred2w + pb * 32 + (d >> 1), *(unsigned*)&ph);
            }
        }
        ++bn; if (gbar(syncw, dead, bn, &s_flag)) return;
    }
}

// ---------------- E1: ca1 = relu(h @ fc_w.T + fc_b), IN PLACE (unchanged) ----------------
__global__ __launch_bounds__(256) void k_fc_inplace(
    float* __restrict__ hist,        // in: h rows, out: ca1 rows  [65536,512]
    const float* __restrict__ fc_w,  // [512,512]
    const float* __restrict__ fc_b)  // [512]
{
    __shared__ __align__(16) float s_a[16 * 516];
    const int tid = threadIdx.x;
    const int r = tid & 15;
    const int jset = tid >> 4;
    const int row0 = blockIdx.x * 16;

    for (int i = tid; i < 2048; i += 256) {
        int rr = i >> 7, f = i & 127;
        float4 v = *(const float4*)(hist + (size_t)(row0 + rr) * H_ + f * 4);
        *(float4*)(s_a + rr * 516 + f * 4) = v;
    }
    __syncthreads();

    float acc[32];
#pragma unroll
    for (int jj = 0; jj < 32; ++jj) acc[jj] = 0.f;

    const float4* arow = (const float4*)(s_a + r * 516);
    for (int k4 = 0; k4 < 128; ++k4) {
        float4 a = arow[k4];
#pragma unroll
        for (int jj = 0; jj < 32; ++jj) {
            int j = jset + (jj << 4);
            float4 w = *(const float4*)(fc_w + (size_t)j * 512 + k4 * 4);
            acc[jj] += a.x * w.x + a.y * w.y + a.z * w.z + a.w * w.w;
        }
    }

    float* crow = hist + (size_t)(row0 + r) * H_;
#pragma unroll
    for (int jj = 0; jj < 32; ++jj) {
        int j = jset + (jj << 4);
        float v = acc[jj] + fc_b[j];
        crow[j] = fmaxf(v, 0.f);
    }
}

// ---------------- E3: q = ca1 @ out_w.T + out_b (unchanged) ----------------
__global__ __launch_bounds__(256) void k_q(
    const float* __restrict__ ca1,   // [65536,512]
    const float* __restrict__ out_w, // [16,512]
    const float* __restrict__ out_b, // [16]
    float* __restrict__ q)           // [65536,16]
{
    __shared__ __align__(16) float s_a[16 * 516];
    __shared__ __align__(16) float s_w[16 * 516];
    const int tid = threadIdx.x;
    const int r = tid >> 4;
    const int a_ = tid & 15;
    const int row0 = blockIdx.x * 16;

    for (int i = tid; i < 2048; i += 256) {
        int rr = i >> 7, f = i & 127;
        float4 v = *(const float4*)(ca1 + (size_t)(row0 + rr) * H_ + f * 4);
        *(float4*)(s_a + rr * 516 + f * 4) = v;
    }
    for (int i = tid; i < 2048; i += 256) {
        int rr = i >> 7, f = i & 127;
        float4 v = *(const float4*)(out_w + (size_t)rr * 512 + f * 4);
        *(float4*)(s_w + rr * 516 + f * 4) = v;
    }
    __syncthreads();

    const float4* arow = (const float4*)(s_a + r * 516);
    const float4* wrow = (const float4*)(s_w + a_ * 516);
    float acc = 0.f;
#pragma unroll 8
    for (int k4 = 0; k4 < 128; ++k4) {
        float4 a = arow[k4];
        float4 w = wrow[k4];
        acc += a.x * w.x + a.y * w.y + a.z * w.z + a.w * w.w;
    }
    q[(size_t)(row0 + r) * A_ + a_] = acc + out_b[a_];
}

// ---------------- host ----------------
extern "C" void kernel_launch(void* const* d_in, const int* in_sizes, int n_in,
                              void* d_out, int out_size, void* d_ws, size_t ws_size,
                              hipStream_t stream) {
    const float* x     = (const float*)d_in[0];
    const float* W_ih  = (const float*)d_in[1];
    const float* W_hh  = (const float*)d_in[2];
    const float* b_ih  = (const float*)d_in[3];
    const float* b_hh  = (const float*)d_in[4];
    const float* fc_w  = (const float*)d_in[5];
    const float* fc_b  = (const float*)d_in[6];
    const float* out_w = (const float*)d_in[7];
    const float* out_b = (const float*)d_in[8];
    const float* cb_w1 = (const float*)d_in[9];
    const float* cb_b1 = (const float*)d_in[10];
    const float* cb_w2 = (const float*)d_in[11];
    const float* cb_b2 = (const float*)d_in[12];

    float* q_out  = (float*)d_out;                     // [64,1024,16]
    float* cbp    = q_out + (size_t)B_ * S_ * A_;      // [64,1024,64]
    float* hidden = cbp + (size_t)B_ * S_ * D_;        // [1,64,512]
    float* ca1    = hidden + (size_t)B_ * H_;          // [64,1024,512] (h-history then ca1)

    uint4* wsu = (uint4*)d_ws;                         // 172608 u4 = 2.76 MB

    k_convert<<<(WS_TOTAL + 255) / 256, 256, 0, stream>>>(W_ih, W_hh, cb_w1, wsu);
    k_recur<<<NWG, 256, 0, stream>>>(wsu,
        (unsigned*)(wsu + OFF_SYNC), wsu + OFF_H2, (float*)(wsu + OFF_U2),
        (unsigned*)(wsu + OFF_PRED2), x, b_ih, b_hh, cb_b1, cb_b2, cb_w2,
        ca1, hidden, cbp);
    k_fc_inplace<<<4096, 256, 0, stream>>>(ca1, fc_w, fc_b);
    k_q<<<4096, 256, 0, stream>>>(ca1, out_w, out_b, q_out);
}

// Round 5
// 73509.296 us; speedup vs baseline: 1.2468x; 1.2468x over previous
//
#include <hip/hip_runtime.h>
#include <hip/hip_fp16.h>

// RecurrentQNet: B=64, S=1024, D=64, H=512, A=16
// R6: slice-parallel persistent recurrence, cache-friendly exchange.
//   R5 post-mortem: FETCH 40GB unchanged vs R4 -> bypass-atomic READS of h/u by
//   all 128 WGs (128x read amplification, 8+ MB/step) + 16k pollers = the cost,
//   not fences. R6:
//   (1) h exchanged through the fp32 hist output itself: bypass-atomic WRITES
//       (write-through to IF), normal CACHED reads of never-before-read
//       addresses (rotating by t) -> per-XCD traffic = one copy, no staleness.
//   (2) u exchanged via rotating u2[1024][64][512] f16, same pattern.
//   (3) pred off critical path: Wf = W_ih_pred @ cb_w2 precomputed (f16) folds
//       pred into the gate GEMM -> 2 grid barriers/step instead of 3; pred
//       computed post-B2 only for the cbp output.
//   (4) relay barrier (WG0 aggregates flags -> one 'go' word): ~255 pollers.
//   Numerics: f16 chains of 16 products flushed to fp32 (R2/R4 passing recipe).

#define B_ 64
#define S_ 1024
#define D_ 64
#define H_ 512
#define A_ 16

#define NWG 128

// ---- workspace byte offsets ----
#define OFF_WHH  0              // [1536][512] f16
#define OFF_WF   1572864        // [1536][512] f16 (W_ih_pred @ cb_w2)
#define OFF_WIX  3145728        // [1536][64]  f16
#define OFF_WU   3342336        // [512][512]  f16 (cb_w1)
#define OFF_WC2  3866624        // [64][512]   f16 (cb_w2)
#define OFF_WFB  3932160        // [1536]      f32 (W_ih_pred @ cb_b2)
#define OFF_SYNC 3940352        // 512 u32: go@0, dead@16, flags@32+wg
#define OFF_U2   4194304        // [1024][64][512] f16 = 64 MB

typedef unsigned long long ull;

union V16 {
    uint4   u;
    float4  f;
    __half2 h[4];
    ull     u64[2];
};
union V8 {
    ull     u;
    float2  f;
    __half2 h2v[2];
};

__device__ __forceinline__ void astore8(ull* p, ull v) {
    __hip_atomic_store(p, v, __ATOMIC_RELAXED, __HIP_MEMORY_SCOPE_AGENT);
}
__device__ __forceinline__ unsigned aload4(const unsigned* p) {
    return __hip_atomic_load(p, __ATOMIC_RELAXED, __HIP_MEMORY_SCOPE_AGENT);
}
__device__ __forceinline__ void astore4(unsigned* p, unsigned v) {
    __hip_atomic_store(p, v, __ATOMIC_RELAXED, __HIP_MEMORY_SCOPE_AGENT);
}

// 64-MAC dot: 4 chains of 16 f16 products, each flushed to fp32
__device__ __forceinline__ void dot64(const uint4* __restrict__ w,
                                      const V16* __restrict__ a, float& acc) {
#pragma unroll
    for (int ch = 0; ch < 4; ++ch) {
        V16 w0, w1;
        w0.u = w[ch * 2]; w1.u = w[ch * 2 + 1];
        __half2 s = __hmul2(w0.h[0], a[ch * 2].h[0]);
        s = __hfma2(w0.h[1], a[ch * 2].h[1], s);
        s = __hfma2(w0.h[2], a[ch * 2].h[2], s);
        s = __hfma2(w0.h[3], a[ch * 2].h[3], s);
        s = __hfma2(w1.h[0], a[ch * 2 + 1].h[0], s);
        s = __hfma2(w1.h[1], a[ch * 2 + 1].h[1], s);
        s = __hfma2(w1.h[2], a[ch * 2 + 1].h[2], s);
        s = __hfma2(w1.h[3], a[ch * 2 + 1].h[3], s);
        float2 f = __half22float2(s);
        acc += f.x + f.y;
    }
}
// 8-MAC dot (x part)
__device__ __forceinline__ void dotx(const uint4* __restrict__ w,
                                     const V16& a, float& acc) {
    V16 w0; w0.u = *w;
    __half2 s = __hmul2(w0.h[0], a.h[0]);
    s = __hfma2(w0.h[1], a.h[1], s);
    s = __hfma2(w0.h[2], a.h[2], s);
    s = __hfma2(w0.h[3], a.h[3], s);
    float2 f = __half22float2(s);
    acc += f.x + f.y;
}

// ---------------- K0a: elementwise f32->f16 weight convert + zero sync ----------------
__global__ __launch_bounds__(256) void k_convert(
    const float* __restrict__ W_ih,   // [1536,128]
    const float* __restrict__ W_hh,   // [1536,512]
    const float* __restrict__ cb_w1,  // [512,512]
    const float* __restrict__ cb_w2,  // [64,512]
    char* __restrict__ ws)
{
    int idx = blockIdx.x * 256 + threadIdx.x;
    if (idx < 393216) {                               // W_hh pairs
        const float* s = W_hh + (size_t)idx * 2;
        ((__half2*)(ws + OFF_WHH))[idx] = __floats2half2_rn(s[0], s[1]);
    } else if (idx < 442368) {                        // W_ih x-cols pairs
        int p = idx - 393216;
        int row = p >> 5, kp = p & 31;
        const float* s = W_ih + (size_t)row * 128 + kp * 2;
        ((__half2*)(ws + OFF_WIX))[p] = __floats2half2_rn(s[0], s[1]);
    } else if (idx < 573440) {                        // cb_w1 pairs
        int p = idx - 442368;
        const float* s = cb_w1 + (size_t)p * 2;
        ((__half2*)(ws + OFF_WU))[p] = __floats2half2_rn(s[0], s[1]);
    } else if (idx < 589824) {                        // cb_w2 pairs
        int p = idx - 573440;
        const float* s = cb_w2 + (size_t)p * 2;
        ((__half2*)(ws + OFF_WC2))[p] = __floats2half2_rn(s[0], s[1]);
    } else if (idx < 589952) {                        // zero sync region (512 u32)
        ((uint4*)(ws + OFF_SYNC))[idx - 589824] = make_uint4(0u, 0u, 0u, 0u);
    }
}

// ---------------- K0b: Wf = W_ih_pred @ cb_w2 (f16), Wfb = W_ih_pred @ cb_b2 ----------------
__global__ __launch_bounds__(256) void k_wf(
    const float* __restrict__ W_ih,   // [1536,128]
    const float* __restrict__ cb_w2,  // [64,512]
    const float* __restrict__ cb_b2,  // [64]
    char* __restrict__ ws)
{
    const int row = blockIdx.x;       // 0..1535
    const int tid = threadIdx.x;      // 0..255
    const int j0 = tid * 2;
    float a0 = 0.f, a1 = 0.f;
    for (int k = 0; k < 64; ++k) {
        float wi = W_ih[(size_t)row * 128 + 64 + k];
        a0 += wi * cb_w2[(size_t)k * 512 + j0];
        a1 += wi * cb_w2[(size_t)k * 512 + j0 + 1];
    }
    ((__half2*)(ws + OFF_WF))[(size_t)row * 256 + tid] = __floats2half2_rn(a0, a1);
    if (tid == 0) {
        float s = 0.f;
        for (int k = 0; k < 64; ++k)
            s += W_ih[(size_t)row * 128 + 64 + k] * cb_b2[k];
        ((float*)(ws + OFF_WFB))[row] = s;
    }
}

// ---------------- relay grid barrier ----------------
__device__ __forceinline__ int poll_ge(unsigned* p, unsigned bn, unsigned* dead) {
    unsigned it = 0;
    while (aload4(p) < bn) {
        __builtin_amdgcn_s_sleep(1);
        if ((++it & 2047u) == 0u) {
            if (aload4(dead) != 0u) return 1;
            if (it > (1u << 24)) {    // residency failure -> bail, don't hang
                astore4(dead, 1u);
                return 1;
            }
        }
    }
    return 0;
}

__device__ __forceinline__ int gbar(unsigned* syncw, unsigned bn, unsigned* s_flag) {
    const int tid = threadIdx.x;
    unsigned* dead = syncw + 16;
    __syncthreads();                       // vmcnt(0): this WG's stores drained
    if (tid == 0) *s_flag = 0u;
    __syncthreads();
    if (tid == 0) astore4(syncw + 32 + blockIdx.x, bn);   // publish arrival
    if (blockIdx.x == 0) {
        if (tid < NWG) {
            if (poll_ge(syncw + 32 + tid, bn, dead)) *s_flag = 1u;
        }
        __syncthreads();                   // all flags seen
        if (tid == 0 && *s_flag == 0u) astore4(syncw, bn);  // publish go
    } else {
        if (tid == 0) {
            if (poll_ge(syncw, bn, dead)) *s_flag = 1u;     // wait for go
        }
        __syncthreads();
    }
    __syncthreads();
    return *s_flag != 0u;
}

// ---------------- K1: slice-parallel recurrence ----------------
// 128 WGs x 512 thr. WG wg: j-slice [4wg,4wg+4). thread: b=tid>>3, c=tid&7.
__global__ __launch_bounds__(512) void k_recur(
    char* __restrict__ ws,
    const float* __restrict__ x,       // [64,1024,64] fp32
    const float* __restrict__ b_ih, const float* __restrict__ b_hh,
    const float* __restrict__ cb_b1, const float* __restrict__ cb_b2,
    float* __restrict__ hist,          // [64,1024,512] (h history = ca1 slot; ALSO h exchange)
    float* __restrict__ hidden,        // [64,512]
    float* __restrict__ cbp)           // [64,1024,64]
{
    __shared__ unsigned s_flag;
    const int tid = threadIdx.x;
    const int wg = blockIdx.x;
    const int b = tid >> 3;
    const int c = tid & 7;
    const int j4 = wg * 4;

    const __half* whh = (const __half*)(ws + OFF_WHH);
    const __half* wfm = (const __half*)(ws + OFF_WF);
    const __half* wix = (const __half*)(ws + OFF_WIX);
    const __half* wu  = (const __half*)(ws + OFF_WU);
    const __half* wc2 = (const __half*)(ws + OFF_WC2);
    const float*  wfb = (const float*)(ws + OFF_WFB);
    unsigned* syncw   = (unsigned*)(ws + OFF_SYNC);
    __half* u2        = (__half*)(ws + OFF_U2);

    float bias_r[4], bias_z[4], bias_ni[4], bias_nh[4], bias_u[4];
    float wfb_r[4], wfb_z[4], wfb_n[4];
#pragma unroll
    for (int jj = 0; jj < 4; ++jj) {
        int j = j4 + jj;
        bias_r[jj]  = b_ih[j] + b_hh[j];
        bias_z[jj]  = b_ih[512 + j] + b_hh[512 + j];
        bias_ni[jj] = b_ih[1024 + j];
        bias_nh[jj] = b_hh[1024 + j];
        bias_u[jj]  = cb_b1[j];
        wfb_r[jj]   = wfb[j];
        wfb_z[jj]   = wfb[512 + j];
        wfb_n[jj]   = wfb[1024 + j];
    }
    // pred-output ownership: WG (pb = wg>>1, d-half = wg&1); thread (dl, ks)
    const int dl = tid >> 4, ks = tid & 15;
    const int pb = wg >> 1, d = (wg & 1) * 32 + dl;
    const float bias_p = cb_b2[d];

    float hprev[4] = {0.f, 0.f, 0.f, 0.f};

    // per-c weight base pointers (uint4 units)
    const uint4* whh4 = (const uint4*)whh + c * 8;   // + row*64
    const uint4* wf4  = (const uint4*)wfm + c * 8;
    const uint4* wix4 = (const uint4*)wix + c;       // + row*8
    const uint4* wu4  = (const uint4*)wu + c * 8;

    unsigned bn = 0;

    for (int t = 0; t < S_; ++t) {
        // ======== P1: gates for j-slice, all batches ========
        V16 hf[8], uf[8], xf;
        if (t > 0) {
            const float4* hp = (const float4*)(hist + ((size_t)b * S_ + (t - 1)) * H_ + c * 64);
#pragma unroll
            for (int q = 0; q < 8; ++q) {
                float4 f0 = hp[q * 2], f1 = hp[q * 2 + 1];
                hf[q].h[0] = __floats2half2_rn(f0.x, f0.y);
                hf[q].h[1] = __floats2half2_rn(f0.z, f0.w);
                hf[q].h[2] = __floats2half2_rn(f1.x, f1.y);
                hf[q].h[3] = __floats2half2_rn(f1.z, f1.w);
            }
            const uint4* up = (const uint4*)(u2 + ((size_t)(t - 1) * 64 + b) * 512 + c * 64);
#pragma unroll
            for (int q = 0; q < 8; ++q) uf[q].u = up[q];
        }
        {
            const float4* xp = (const float4*)(x + ((size_t)b * S_ + t) * D_ + c * 8);
            float4 f0 = xp[0], f1 = xp[1];
            xf.h[0] = __floats2half2_rn(f0.x, f0.y);
            xf.h[1] = __floats2half2_rn(f0.z, f0.w);
            xf.h[2] = __floats2half2_rn(f1.x, f1.y);
            xf.h[3] = __floats2half2_rn(f1.z, f1.w);
        }

        float accrz[8], gin[4], ghn[4];
#pragma unroll
        for (int i = 0; i < 8; ++i) accrz[i] = 0.f;
#pragma unroll
        for (int i = 0; i < 4; ++i) { gin[i] = 0.f; ghn[i] = 0.f; }

        if (t > 0) {
#pragma unroll
            for (int jj = 0; jj < 4; ++jj) {
                dot64(whh4 + (size_t)(j4 + jj) * 64,        hf, accrz[jj]);
                dot64(whh4 + (size_t)(512 + j4 + jj) * 64,  hf, accrz[4 + jj]);
                dot64(whh4 + (size_t)(1024 + j4 + jj) * 64, hf, ghn[jj]);
                dot64(wf4  + (size_t)(j4 + jj) * 64,        uf, accrz[jj]);
                dot64(wf4  + (size_t)(512 + j4 + jj) * 64,  uf, accrz[4 + jj]);
                dot64(wf4  + (size_t)(1024 + j4 + jj) * 64, uf, gin[jj]);
            }
        }
#pragma unroll
        for (int jj = 0; jj < 4; ++jj) {
            dotx(wix4 + (size_t)(j4 + jj) * 8,        xf, accrz[jj]);
            dotx(wix4 + (size_t)(512 + j4 + jj) * 8,  xf, accrz[4 + jj]);
            dotx(wix4 + (size_t)(1024 + j4 + jj) * 8, xf, gin[jj]);
        }
#pragma unroll
        for (int i = 0; i < 8; ++i) {
            accrz[i] += __shfl_xor(accrz[i], 1);
            accrz[i] += __shfl_xor(accrz[i], 2);
            accrz[i] += __shfl_xor(accrz[i], 4);
        }
#pragma unroll
        for (int i = 0; i < 4; ++i) {
            gin[i] += __shfl_xor(gin[i], 1);
            gin[i] += __shfl_xor(gin[i], 2);
            gin[i] += __shfl_xor(gin[i], 4);
            ghn[i] += __shfl_xor(ghn[i], 1);
            ghn[i] += __shfl_xor(ghn[i], 2);
            ghn[i] += __shfl_xor(ghn[i], 4);
        }
        if (c == 0) {
            float h[4];
#pragma unroll
            for (int jj = 0; jj < 4; ++jj) {
                float br = bias_r[jj] + (t > 0 ? wfb_r[jj] : 0.f);
                float bz = bias_z[jj] + (t > 0 ? wfb_z[jj] : 0.f);
                float bn_ = bias_ni[jj] + (t > 0 ? wfb_n[jj] : 0.f);
                float rr = 1.f / (1.f + __expf(-(accrz[jj] + br)));
                float zz = 1.f / (1.f + __expf(-(accrz[4 + jj] + bz)));
                float nn = tanhf(gin[jj] + bn_ + rr * (ghn[jj] + bias_nh[jj]));
                h[jj] = (1.f - zz) * nn + zz * hprev[jj];
                hprev[jj] = h[jj];
            }
            // h exchange = hist itself: bypass-atomic write-through (agent-visible)
            V8 p0, p1;
            p0.f = make_float2(h[0], h[1]);
            p1.f = make_float2(h[2], h[3]);
            ull* hw = (ull*)(hist + ((size_t)b * S_ + t) * H_ + j4);
            astore8(hw, p0.u);
            astore8(hw + 1, p1.u);
            if (t == S_ - 1)
                *(float4*)(hidden + (size_t)b * H_ + j4) = make_float4(h[0], h[1], h[2], h[3]);
        }
        ++bn; if (gbar(syncw, bn, &s_flag)) return;

        // ======== P2: u = relu(cb_w1 @ h_t + b1) ========
        {
            V16 hc[8];
            const float4* hp = (const float4*)(hist + ((size_t)b * S_ + t) * H_ + c * 64);
#pragma unroll
            for (int q = 0; q < 8; ++q) {
                float4 f0 = hp[q * 2], f1 = hp[q * 2 + 1];
                hc[q].h[0] = __floats2half2_rn(f0.x, f0.y);
                hc[q].h[1] = __floats2half2_rn(f0.z, f0.w);
                hc[q].h[2] = __floats2half2_rn(f1.x, f1.y);
                hc[q].h[3] = __floats2half2_rn(f1.z, f1.w);
            }
            float uacc[4] = {0.f, 0.f, 0.f, 0.f};
#pragma unroll
            for (int jr = 0; jr < 4; ++jr)
                dot64(wu4 + (size_t)(j4 + jr) * 64, hc, uacc[jr]);
#pragma unroll
            for (int i = 0; i < 4; ++i) {
                uacc[i] += __shfl_xor(uacc[i], 1);
                uacc[i] += __shfl_xor(uacc[i], 2);
                uacc[i] += __shfl_xor(uacc[i], 4);
            }
            if (c == 0) {
                V8 pk;
                pk.h2v[0] = __floats2half2_rn(fmaxf(uacc[0] + bias_u[0], 0.f),
                                              fmaxf(uacc[1] + bias_u[1], 0.f));
                pk.h2v[1] = __floats2half2_rn(fmaxf(uacc[2] + bias_u[2], 0.f),
                                              fmaxf(uacc[3] + bias_u[3], 0.f));
                astore8((ull*)(u2 + ((size_t)t * 64 + b) * 512 + j4), pk.u);
            }
        }
        ++bn; if (gbar(syncw, bn, &s_flag)) return;

        // ======== P3 (off critical path): pred -> cbp output ========
        {
            const uint4* uq = (const uint4*)(u2 + ((size_t)t * 64 + pb) * 512 + ks * 32);
            const uint4* wq = (const uint4*)(wc2 + (size_t)d * 512 + ks * 32);
            float pacc = 0.f;
#pragma unroll
            for (int ch = 0; ch < 2; ++ch) {
                V16 w0, w1, a0, a1;
                w0.u = wq[ch * 2]; w1.u = wq[ch * 2 + 1];
                a0.u = uq[ch * 2]; a1.u = uq[ch * 2 + 1];
                __half2 s = __hmul2(w0.h[0], a0.h[0]);
                s = __hfma2(w0.h[1], a0.h[1], s);
                s = __hfma2(w0.h[2], a0.h[2], s);
                s = __hfma2(w0.h[3], a0.h[3], s);
                s = __hfma2(w1.h[0], a1.h[0], s);
                s = __hfma2(w1.h[1], a1.h[1], s);
                s = __hfma2(w1.h[2], a1.h[2], s);
                s = __hfma2(w1.h[3], a1.h[3], s);
                float2 f = __half22float2(s);
                pacc += f.x + f.y;
            }
            pacc += __shfl_xor(pacc, 1);
            pacc += __shfl_xor(pacc, 2);
            pacc += __shfl_xor(pacc, 4);
            pacc += __shfl_xor(pacc, 8);
            if (ks == 0)
                cbp[((size_t)pb * S_ + t) * 64 + d] = pacc + bias_p;
        }
    }
}

// ---------------- E1: ca1 = relu(h @ fc_w.T + fc_b), IN PLACE (unchanged) ----------------
__global__ __launch_bounds__(256) void k_fc_inplace(
    float* __restrict__ hist,        // in: h rows, out: ca1 rows  [65536,512]
    const float* __restrict__ fc_w,  // [512,512]
    const float* __restrict__ fc_b)  // [512]
{
    __shared__ __align__(16) float s_a[16 * 516];
    const int tid = threadIdx.x;
    const int r = tid & 15;
    const int jset = tid >> 4;
    const int row0 = blockIdx.x * 16;

    for (int i = tid; i < 2048; i += 256) {
        int rr = i >> 7, f = i & 127;
        float4 v = *(const float4*)(hist + (size_t)(row0 + rr) * H_ + f * 4);
        *(float4*)(s_a + rr * 516 + f * 4) = v;
    }
    __syncthreads();

    float acc[32];
#pragma unroll
    for (int jj = 0; jj < 32; ++jj) acc[jj] = 0.f;

    const float4* arow = (const float4*)(s_a + r * 516);
    for (int k4 = 0; k4 < 128; ++k4) {
        float4 a = arow[k4];
#pragma unroll
        for (int jj = 0; jj < 32; ++jj) {
            int j = jset + (jj << 4);
            float4 w = *(const float4*)(fc_w + (size_t)j * 512 + k4 * 4);
            acc[jj] += a.x * w.x + a.y * w.y + a.z * w.z + a.w * w.w;
        }
    }

    float* crow = hist + (size_t)(row0 + r) * H_;
#pragma unroll
    for (int jj = 0; jj < 32; ++jj) {
        int j = jset + (jj << 4);
        float v = acc[jj] + fc_b[j];
        crow[j] = fmaxf(v, 0.f);
    }
}

// ---------------- E3: q = ca1 @ out_w.T + out_b (unchanged) ----------------
__global__ __launch_bounds__(256) void k_q(
    const float* __restrict__ ca1,   // [65536,512]
    const float* __restrict__ out_w, // [16,512]
    const float* __restrict__ out_b, // [16]
    float* __restrict__ q)           // [65536,16]
{
    __shared__ __align__(16) float s_a[16 * 516];
    __shared__ __align__(16) float s_w[16 * 516];
    const int tid = threadIdx.x;
    const int r = tid >> 4;
    const int a_ = tid & 15;
    const int row0 = blockIdx.x * 16;

    for (int i = tid; i < 2048; i += 256) {
        int rr = i >> 7, f = i & 127;
        float4 v = *(const float4*)(ca1 + (size_t)(row0 + rr) * H_ + f * 4);
        *(float4*)(s_a + rr * 516 + f * 4) = v;
    }
    for (int i = tid; i < 2048; i += 256) {
        int rr = i >> 7, f = i & 127;
        float4 v = *(const float4*)(out_w + (size_t)rr * 512 + f * 4);
        *(float4*)(s_w + rr * 516 + f * 4) = v;
    }
    __syncthreads();

    const float4* arow = (const float4*)(s_a + r * 516);
    const float4* wrow = (const float4*)(s_w + a_ * 516);
    float acc = 0.f;
#pragma unroll 8
    for (int k4 = 0; k4 < 128; ++k4) {
        float4 a = arow[k4];
        float4 w = wrow[k4];
        acc += a.x * w.x + a.y * w.y + a.z * w.z + a.w * w.w;
    }
    q[(size_t)(row0 + r) * A_ + a_] = acc + out_b[a_];
}

// ---------------- host ----------------
extern "C" void kernel_launch(void* const* d_in, const int* in_sizes, int n_in,
                              void* d_out, int out_size, void* d_ws, size_t ws_size,
                              hipStream_t stream) {
    const float* x     = (const float*)d_in[0];
    const float* W_ih  = (const float*)d_in[1];
    const float* W_hh  = (const float*)d_in[2];
    const float* b_ih  = (const float*)d_in[3];
    const float* b_hh  = (const float*)d_in[4];
    const float* fc_w  = (const float*)d_in[5];
    const float* fc_b  = (const float*)d_in[6];
    const float* out_w = (const float*)d_in[7];
    const float* out_b = (const float*)d_in[8];
    const float* cb_w1 = (const float*)d_in[9];
    const float* cb_b1 = (const float*)d_in[10];
    const float* cb_w2 = (const float*)d_in[11];
    const float* cb_b2 = (const float*)d_in[12];

    float* q_out  = (float*)d_out;                     // [64,1024,16]
    float* cbp    = q_out + (size_t)B_ * S_ * A_;      // [64,1024,64]
    float* hidden = cbp + (size_t)B_ * S_ * D_;        // [1,64,512]
    float* ca1    = hidden + (size_t)B_ * H_;          // [64,1024,512] (h-history then ca1)

    char* ws = (char*)d_ws;                            // 68 MB used

    k_convert<<<2305, 256, 0, stream>>>(W_ih, W_hh, cb_w1, cb_w2, ws);
    k_wf<<<1536, 256, 0, stream>>>(W_ih, cb_w2, cb_b2, ws);
    k_recur<<<NWG, 512, 0, stream>>>(ws, x, b_ih, b_hh, cb_b1, cb_b2,
                                     ca1, hidden, cbp);
    k_fc_inplace<<<4096, 256, 0, stream>>>(ca1, fc_w, fc_b);
    k_q<<<4096, 256, 0, stream>>>(ca1, out_w, out_b, q_out);
}

// Round 6
// 37145.813 us; speedup vs baseline: 2.4674x; 1.9789x over previous
//
#include <hip/hip_runtime.h>
#include <hip/hip_fp16.h>

// RecurrentQNet: B=64, S=1024, D=64, H=512, A=16
// R7: XCD-local teams. R6 post-mortem: cross-XCD flag hops cost 15-35us each
// (same order as a kernel launch) -> any grid-wide per-step barrier >= 20ms.
// R7 runs 8 independent teams (one per XCD, 8 batches each, 32 WGs):
//   - team barrier = workgroup-scope atomic RMW (executes at the XCD's L2,
//     ~300cy); polls via CAS (non-idempotent -> not foldable to plain load).
//   - exchange: plain stores (L1 write-through -> L2) + sc0 inline-asm reads
//     (L1-bypass, L2-served). Zero IF traffic in steady state.
//   - weights (3.9MB f16, swizzled) stay L2-resident per XCD for all 1024 steps.
//   - teams formed from HW_REG_XCC_ID (runtime-verified); if any XCD != 32 WGs,
//     fall back to agent-scope (IF) barriers + bypass writes + sc0sc1 reads
//     (R6-proven coherent, slower, still correct).
//   - pred off critical path via Wf = W_ih_pred @ cb_w2 (R6-proven numerics);
//     cbp recomputed from stored u in epilogue GEMM. 2 barriers/step.

#define B_ 64
#define S_ 1024
#define D_ 64
#define H_ 512
#define A_ 16

#define NWG 256
#define THR 512

// ---- workspace byte offsets ----
#define OFF_WGG  0u          // [32][3][16][8][8] u4 : W_hh swizzled f16
#define OFF_WFG  1572864u    // same shape: Wf = W_ih_pred @ cb_w2
#define OFF_WIX  3145728u    // [32][3][16][8] u4 : W_ih x-cols f16
#define OFF_WU1  3342336u    // [32][16][8][8] u4 : cb_w1 f16
#define OFF_WC2  3866624u    // [64][512] f16 : cb_w2 (epilogue)
#define OFF_WFB  3932160u    // [1536] f32 : W_ih_pred @ cb_b2
#define OFF_SYNC 3938304u    // 2048 u32 (8KB)
#define OFF_H2   3946496u    // [2][64][512] f16 ping-pong
#define OFF_U2   4077568u    // [2][64][512] f16 ping-pong
#define OFF_U2F  4208640u    // [1024][64][512] f16 (u history for epilogue)

// sync word indices
#define SY_GCNT 0
#define SY_GGO  64
#define SY_DEAD 128
#define SY_MBAD 192
#define SY_XCNT 256          // + xcd*64
#define SY_TEAM 1024         // + team*128 (cnt); +64 (go)

typedef unsigned uv4 __attribute__((ext_vector_type(4)));

union V16 {
    uint4   u;
    float4  f;
    __half2 h[4];
    uv4     ev;
};

// ---- atomic helpers (scope chosen at each call site; CAS-read unfoldable) ----
__device__ __forceinline__ unsigned rmw_add(unsigned* p, unsigned v, bool agent) {
    if (agent) return __hip_atomic_fetch_add(p, v, __ATOMIC_RELAXED, __HIP_MEMORY_SCOPE_AGENT);
    return __hip_atomic_fetch_add(p, v, __ATOMIC_RELAXED, __HIP_MEMORY_SCOPE_WORKGROUP);
}
__device__ __forceinline__ unsigned rmw_read(unsigned* p, unsigned expect, bool agent) {
    unsigned e = expect;
    if (agent) __hip_atomic_compare_exchange_strong(p, &e, expect, __ATOMIC_RELAXED, __ATOMIC_RELAXED, __HIP_MEMORY_SCOPE_AGENT);
    else       __hip_atomic_compare_exchange_strong(p, &e, expect, __ATOMIC_RELAXED, __ATOMIC_RELAXED, __HIP_MEMORY_SCOPE_WORKGROUP);
    return e;   // old value
}

// ---- exchange reads: sc0 (fast, L2-served) / sc0 sc1 (slow, IF-served) ----
__device__ __forceinline__ void xread8(V16* d, const uint4* p, bool slow) {
    uv4 a0, a1, a2, a3, a4, a5, a6, a7;
    if (slow) {
        asm volatile(
            "global_load_dwordx4 %0, %8, off sc0 sc1\n\t"
            "global_load_dwordx4 %1, %8, off offset:16 sc0 sc1\n\t"
            "global_load_dwordx4 %2, %8, off offset:32 sc0 sc1\n\t"
            "global_load_dwordx4 %3, %8, off offset:48 sc0 sc1\n\t"
            "global_load_dwordx4 %4, %8, off offset:64 sc0 sc1\n\t"
            "global_load_dwordx4 %5, %8, off offset:80 sc0 sc1\n\t"
            "global_load_dwordx4 %6, %8, off offset:96 sc0 sc1\n\t"
            "global_load_dwordx4 %7, %8, off offset:112 sc0 sc1\n\t"
            "s_waitcnt vmcnt(0)"
            : "=&v"(a0), "=&v"(a1), "=&v"(a2), "=&v"(a3),
              "=&v"(a4), "=&v"(a5), "=&v"(a6), "=&v"(a7)
            : "v"(p));
    } else {
        asm volatile(
            "global_load_dwordx4 %0, %8, off sc0\n\t"
            "global_load_dwordx4 %1, %8, off offset:16 sc0\n\t"
            "global_load_dwordx4 %2, %8, off offset:32 sc0\n\t"
            "global_load_dwordx4 %3, %8, off offset:48 sc0\n\t"
            "global_load_dwordx4 %4, %8, off offset:64 sc0\n\t"
            "global_load_dwordx4 %5, %8, off offset:80 sc0\n\t"
            "global_load_dwordx4 %6, %8, off offset:96 sc0\n\t"
            "global_load_dwordx4 %7, %8, off offset:112 sc0\n\t"
            "s_waitcnt vmcnt(0)"
            : "=&v"(a0), "=&v"(a1), "=&v"(a2), "=&v"(a3),
              "=&v"(a4), "=&v"(a5), "=&v"(a6), "=&v"(a7)
            : "v"(p));
    }
    d[0].ev = a0; d[1].ev = a1; d[2].ev = a2; d[3].ev = a3;
    d[4].ev = a4; d[5].ev = a5; d[6].ev = a6; d[7].ev = a7;
}

__device__ __forceinline__ void xwrite4(unsigned* p, unsigned v, bool slow) {
    if (slow) __hip_atomic_store(p, v, __ATOMIC_RELAXED, __HIP_MEMORY_SCOPE_AGENT);
    else      *p = v;
}

// 64-MAC dot: 4 chains of 16 f16 products, each flushed to fp32 (R4/R6 recipe)
__device__ __forceinline__ void dot64(const uint4* __restrict__ w,
                                      const V16* __restrict__ a, float& acc) {
#pragma unroll
    for (int ch = 0; ch < 4; ++ch) {
        V16 w0, w1;
        w0.u = w[ch * 2]; w1.u = w[ch * 2 + 1];
        __half2 s = __hmul2(w0.h[0], a[ch * 2].h[0]);
        s = __hfma2(w0.h[1], a[ch * 2].h[1], s);
        s = __hfma2(w0.h[2], a[ch * 2].h[2], s);
        s = __hfma2(w0.h[3], a[ch * 2].h[3], s);
        s = __hfma2(w1.h[0], a[ch * 2 + 1].h[0], s);
        s = __hfma2(w1.h[1], a[ch * 2 + 1].h[1], s);
        s = __hfma2(w1.h[2], a[ch * 2 + 1].h[2], s);
        s = __hfma2(w1.h[3], a[ch * 2 + 1].h[3], s);
        float2 f = __half22float2(s);
        acc += f.x + f.y;
    }
}
// 8-MAC dot (x part)
__device__ __forceinline__ void dotx(const uint4* __restrict__ w,
                                     const V16& a, float& acc) {
    V16 w0; w0.u = *w;
    __half2 s = __hmul2(w0.h[0], a.h[0]);
    s = __hfma2(w0.h[1], a.h[1], s);
    s = __hfma2(w0.h[2], a.h[2], s);
    s = __hfma2(w0.h[3], a.h[3], s);
    float2 f = __half22float2(s);
    acc += f.x + f.y;
}

// ---------------- K0a: weight swizzle/convert + wfb + zero sync ----------------
// wgg/wfg layout u4 idx = (w*3+g)*1024 + jj*64 + kq*8 + i (jj<16, kq<8, i<8)
// wix  layout u4 idx = (w*3+g)*128 + jj*8 + kq
// wu1  layout u4 idx = w*1024 + jj*64 + kq*8 + i
__global__ __launch_bounds__(256) void k_convert(
    const float* __restrict__ W_ih,   // [1536,128]
    const float* __restrict__ W_hh,   // [1536,512]
    const float* __restrict__ cb_w1,  // [512,512]
    const float* __restrict__ cb_w2,  // [64,512]
    const float* __restrict__ cb_b2,  // [64]
    char* __restrict__ ws)
{
    int idx = blockIdx.x * 256 + threadIdx.x;
    const float* src = nullptr;
    uint4* dst = nullptr;
    if (idx < 98304) {                                  // wgg
        int w = idx / 3072, r1 = idx % 3072;
        int g = r1 / 1024, r2 = r1 % 1024;
        int jj = r2 >> 6, kq = (r2 >> 3) & 7, i = r2 & 7;
        src = W_hh + (size_t)(g * 512 + w * 16 + jj) * 512 + kq * 64 + i * 8;
        dst = (uint4*)(ws + OFF_WGG) + idx;
    } else if (idx < 110592) {                          // wix
        int p = idx - 98304;
        int w = p / 384, r1 = p % 384;
        int g = r1 / 128, r2 = r1 % 128;
        int jj = r2 >> 3, kq = r2 & 7;
        src = W_ih + (size_t)(g * 512 + w * 16 + jj) * 128 + kq * 8;
        dst = (uint4*)(ws + OFF_WIX) + p;
    } else if (idx < 143360) {                          // wu1
        int p = idx - 110592;
        int w = p / 1024, r2 = p % 1024;
        int jj = r2 >> 6, kq = (r2 >> 3) & 7, i = r2 & 7;
        src = cb_w1 + (size_t)(w * 16 + jj) * 512 + kq * 64 + i * 8;
        dst = (uint4*)(ws + OFF_WU1) + p;
    } else if (idx < 147456) {                          // wc2 (natural)
        int p = idx - 143360;
        src = cb_w2 + (size_t)p * 8;
        dst = (uint4*)(ws + OFF_WC2) + p;
    } else if (idx < 148992) {                          // wfb
        int row = idx - 147456;
        float s = 0.f;
        for (int k = 0; k < 64; ++k)
            s += W_ih[(size_t)row * 128 + 64 + k] * cb_b2[k];
        ((float*)(ws + OFF_WFB))[row] = s;
        return;
    } else if (idx < 151040) {                          // zero sync (2048 u32)
        ((unsigned*)(ws + OFF_SYNC))[idx - 148992] = 0u;
        return;
    } else return;
    V16 o;
#pragma unroll
    for (int i = 0; i < 4; ++i) o.h[i] = __floats2half2_rn(src[2 * i], src[2 * i + 1]);
    *dst = o.u;
}

// ---------------- K0b: Wf = W_ih_pred @ cb_w2 (f16, swizzled) ----------------
__global__ __launch_bounds__(256) void k_wf(
    const float* __restrict__ W_ih,   // [1536,128]
    const float* __restrict__ cb_w2,  // [64,512]
    char* __restrict__ ws)
{
    int idx = blockIdx.x * 256 + threadIdx.x;   // < 98304
    int w = idx / 3072, r1 = idx % 3072;
    int g = r1 / 1024, r2 = r1 % 1024;
    int jj = r2 >> 6, kq = (r2 >> 3) & 7, i = r2 & 7;
    int row = g * 512 + w * 16 + jj;
    int col0 = kq * 64 + i * 8;
    float a[8];
#pragma unroll
    for (int m = 0; m < 8; ++m) a[m] = 0.f;
    for (int k = 0; k < 64; ++k) {
        float wi = W_ih[(size_t)row * 128 + 64 + k];
        const float4* c = (const float4*)(cb_w2 + (size_t)k * 512 + col0);
        float4 c0 = c[0], c1 = c[1];
        a[0] += wi * c0.x; a[1] += wi * c0.y; a[2] += wi * c0.z; a[3] += wi * c0.w;
        a[4] += wi * c1.x; a[5] += wi * c1.y; a[6] += wi * c1.z; a[7] += wi * c1.w;
    }
    V16 o;
#pragma unroll
    for (int m = 0; m < 4; ++m) o.h[m] = __floats2half2_rn(a[2 * m], a[2 * m + 1]);
    ((uint4*)(ws + OFF_WFG))[idx] = o.u;
}

// ---------------- team barrier ----------------
__device__ __forceinline__ int tbar(unsigned* sy, int team, unsigned bn,
                                    bool agent, unsigned* s_flag) {
    __syncthreads();                        // drain this WG's stores (vmcnt 0)
    unsigned* cnt = sy + SY_TEAM + team * 128;
    unsigned* go  = cnt + 64;
    if (threadIdx.x == 0) {
        *s_flag = 0u;
        unsigned old = rmw_add(cnt, 1u, agent);
        if (old == 32u * bn - 1u) {
            rmw_add(go, 1u, agent);         // go becomes bn
        } else {
            unsigned it = 0;
            for (;;) {
                if (rmw_read(go, bn, agent) >= bn) break;
                __builtin_amdgcn_s_sleep(1);
                if ((++it & 2047u) == 0u) {
                    if (rmw_read(sy + SY_DEAD, 1u, true) != 0u) { *s_flag = 1u; break; }
                    if (it > (1u << 22)) { rmw_add(sy + SY_DEAD, 1u, true); *s_flag = 1u; break; }
                }
            }
        }
    }
    __syncthreads();
    return *s_flag != 0u;
}

// ---------------- K1: XCD-team recurrence ----------------
// 256 WGs x 512 thr. Team (XCD) owns batches team*8..+7; member owns j-slice
// [member*16, member*16+16). Thread: wave wv=tid>>6 -> jj={wv*2, wv*2+1};
// lane: b8=ln>>3 (batch in team), kq=ln&7 (K/8-slice of 64).
__global__ __launch_bounds__(512) void k_recur(
    char* __restrict__ ws,
    const float* __restrict__ x,       // [64,1024,64] fp32
    const float* __restrict__ b_ih, const float* __restrict__ b_hh,
    const float* __restrict__ cb_b1,
    float* __restrict__ hist,          // [64,1024,512]
    float* __restrict__ hidden)        // [64,512]
{
    __shared__ unsigned s_bc[4];       // 0=flag 1=xcd 2=slot 3=mode
    const int tid = threadIdx.x;
    unsigned* sy = (unsigned*)(ws + OFF_SYNC);

    // ---- registration: which XCD am I actually on? ----
    if (tid == 0) {
        unsigned xcd;
        asm volatile("s_getreg_b32 %0, hwreg(HW_REG_XCC_ID)" : "=s"(xcd));
        xcd &= 0xFu;
        unsigned slot = 0xFFu;
        if (xcd < 8u) {
            slot = rmw_add(sy + SY_XCNT + xcd * 64, 1u, true);
            if (slot >= 32u) rmw_add(sy + SY_MBAD, 1u, true);
        } else {
            rmw_add(sy + SY_MBAD, 1u, true);
        }
        s_bc[0] = 0u; s_bc[1] = xcd; s_bc[2] = slot;
    }
    __syncthreads();
    // ---- one global (agent/IF) barrier, then decide mode ----
    if (tid == 0) {
        unsigned old = rmw_add(sy + SY_GCNT, 1u, true);
        if (old == 255u) rmw_add(sy + SY_GGO, 1u, true);
        else {
            unsigned it = 0;
            for (;;) {
                if (rmw_read(sy + SY_GGO, 1u, true) >= 1u) break;
                __builtin_amdgcn_s_sleep(2);
                if ((++it & 1023u) == 0u) {
                    if (rmw_read(sy + SY_DEAD, 1u, true) != 0u) { s_bc[0] = 1u; break; }
                    if (it > (1u << 22)) { rmw_add(sy + SY_DEAD, 1u, true); s_bc[0] = 1u; break; }
                }
            }
        }
        bool fast = (rmw_read(sy + SY_MBAD, 0u, true) == 0u);
        if (fast)
            for (int xx = 0; xx < 8; ++xx)
                if (rmw_read(sy + SY_XCNT + xx * 64, 0u, true) != 32u) { fast = false; break; }
        s_bc[3] = fast ? 1u : 0u;
    }
    __syncthreads();
    if (s_bc[0] != 0u) return;
    const bool slowm = (s_bc[3] == 0u);
    const int team = slowm ? (int)(blockIdx.x & 7) : (int)s_bc[1];
    const int mem  = slowm ? (int)(blockIdx.x >> 3) : (int)s_bc[2];

    const int wv = tid >> 6, ln = tid & 63;
    const int b8 = ln >> 3, kq = ln & 7;
    const int bg = team * 8 + b8;                 // global batch
    const int jA = mem * 16 + wv * 2;             // even

    const uint4* wgg4 = (const uint4*)(ws + OFF_WGG);
    const uint4* wfg4 = (const uint4*)(ws + OFF_WFG);
    const uint4* wix4 = (const uint4*)(ws + OFF_WIX);
    const uint4* wu14 = (const uint4*)(ws + OFF_WU1);
    const float* wfb  = (const float*)(ws + OFF_WFB);
    const uint4* h2u4 = (const uint4*)(ws + OFF_H2);
    const uint4* u2u4 = (const uint4*)(ws + OFF_U2);
    unsigned* h2w = (unsigned*)(ws + OFF_H2);
    unsigned* u2w = (unsigned*)(ws + OFF_U2);
    unsigned* u2f = (unsigned*)(ws + OFF_U2F);

    float bias_r[2], bias_z[2], b_in[2], b_hn[2], b1v[2], wfr[2], wfz[2], wfn[2];
#pragma unroll
    for (int jx = 0; jx < 2; ++jx) {
        int j = jA + jx;
        bias_r[jx] = b_ih[j] + b_hh[j];
        bias_z[jx] = b_ih[512 + j] + b_hh[512 + j];
        b_in[jx]   = b_ih[1024 + j];
        b_hn[jx]   = b_hh[1024 + j];
        b1v[jx]    = cb_b1[j];
        wfr[jx]    = wfb[j];
        wfz[jx]    = wfb[512 + j];
        wfn[jx]    = wfb[1024 + j];
    }
    float hprev[2] = {0.f, 0.f};
    unsigned bno = 0;

    for (int t = 0; t < S_; ++t) {
        const int slot = t & 1;

        // ======== P1: gates -> h_t ========
        float accr[2] = {0.f, 0.f}, accz[2] = {0.f, 0.f};
        float gin[2] = {0.f, 0.f}, ghn[2] = {0.f, 0.f};
        {   // x part (always)
            const float4* xp = (const float4*)(x + ((size_t)bg * S_ + t) * D_ + kq * 8);
            float4 f0 = xp[0], f1 = xp[1];
            V16 xa;
            xa.h[0] = __floats2half2_rn(f0.x, f0.y);
            xa.h[1] = __floats2half2_rn(f0.z, f0.w);
            xa.h[2] = __floats2half2_rn(f1.x, f1.y);
            xa.h[3] = __floats2half2_rn(f1.z, f1.w);
#pragma unroll
            for (int jx = 0; jx < 2; ++jx) {
                int jo = (wv * 2 + jx) * 8 + kq;
                dotx(wix4 + ((mem * 3 + 0) * 128 + jo), xa, accr[jx]);
                dotx(wix4 + ((mem * 3 + 1) * 128 + jo), xa, accz[jx]);
                dotx(wix4 + ((mem * 3 + 2) * 128 + jo), xa, gin[jx]);
            }
        }
        if (t > 0) {
            V16 hA[8], uA[8];
            xread8(hA, h2u4 + (size_t)((slot ^ 1) * 64 + bg) * 64 + kq * 8, slowm);
            xread8(uA, u2u4 + (size_t)((slot ^ 1) * 64 + bg) * 64 + kq * 8, slowm);
#pragma unroll
            for (int jx = 0; jx < 2; ++jx) {
                int jrow = (wv * 2 + jx) * 64 + kq * 8;
                dot64(wgg4 + (size_t)(mem * 3 + 0) * 1024 + jrow, hA, accr[jx]);
                dot64(wgg4 + (size_t)(mem * 3 + 1) * 1024 + jrow, hA, accz[jx]);
                dot64(wgg4 + (size_t)(mem * 3 + 2) * 1024 + jrow, hA, ghn[jx]);
                dot64(wfg4 + (size_t)(mem * 3 + 0) * 1024 + jrow, uA, accr[jx]);
                dot64(wfg4 + (size_t)(mem * 3 + 1) * 1024 + jrow, uA, accz[jx]);
                dot64(wfg4 + (size_t)(mem * 3 + 2) * 1024 + jrow, uA, gin[jx]);
            }
        }
#pragma unroll
        for (int jx = 0; jx < 2; ++jx) {
            accr[jx] += __shfl_xor(accr[jx], 1); accr[jx] += __shfl_xor(accr[jx], 2); accr[jx] += __shfl_xor(accr[jx], 4);
            accz[jx] += __shfl_xor(accz[jx], 1); accz[jx] += __shfl_xor(accz[jx], 2); accz[jx] += __shfl_xor(accz[jx], 4);
            gin[jx]  += __shfl_xor(gin[jx], 1);  gin[jx]  += __shfl_xor(gin[jx], 2);  gin[jx]  += __shfl_xor(gin[jx], 4);
            ghn[jx]  += __shfl_xor(ghn[jx], 1);  ghn[jx]  += __shfl_xor(ghn[jx], 2);  ghn[jx]  += __shfl_xor(ghn[jx], 4);
        }
        float hnew[2];
#pragma unroll
        for (int jx = 0; jx < 2; ++jx) {
            float br = bias_r[jx] + (t > 0 ? wfr[jx] : 0.f);
            float bz = bias_z[jx] + (t > 0 ? wfz[jx] : 0.f);
            float bn_ = b_in[jx] + (t > 0 ? wfn[jx] : 0.f);
            float rr = 1.f / (1.f + __expf(-(accr[jx] + br)));
            float zz = 1.f / (1.f + __expf(-(accz[jx] + bz)));
            float nn = tanhf(gin[jx] + bn_ + rr * (ghn[jx] + b_hn[jx]));
            hnew[jx] = (1.f - zz) * nn + zz * hprev[jx];
            hprev[jx] = hnew[jx];
        }
        if (kq == 0) {
            *(float2*)(hist + ((size_t)bg * S_ + t) * H_ + jA) = make_float2(hnew[0], hnew[1]);
            if (t == S_ - 1)
                *(float2*)(hidden + (size_t)bg * H_ + jA) = make_float2(hnew[0], hnew[1]);
            __half2 hp2 = __floats2half2_rn(hnew[0], hnew[1]);
            xwrite4(h2w + (size_t)(slot * 64 + bg) * 256 + (jA >> 1), *(unsigned*)&hp2, slowm);
        }
        ++bno; if (tbar(sy, team, bno, slowm, s_bc)) return;

        // ======== P2: u_t = relu(cb_w1 @ h_t + b1) ========
        {
            V16 hB[8];
            xread8(hB, h2u4 + (size_t)(slot * 64 + bg) * 64 + kq * 8, slowm);
            float ua[2] = {0.f, 0.f};
#pragma unroll
            for (int jx = 0; jx < 2; ++jx)
                dot64(wu14 + (size_t)mem * 1024 + (wv * 2 + jx) * 64 + kq * 8, hB, ua[jx]);
#pragma unroll
            for (int jx = 0; jx < 2; ++jx) {
                ua[jx] += __shfl_xor(ua[jx], 1);
                ua[jx] += __shfl_xor(ua[jx], 2);
                ua[jx] += __shfl_xor(ua[jx], 4);
            }
            if (kq == 0) {
                float u0 = fmaxf(ua[0] + b1v[0], 0.f);
                float u1 = fmaxf(ua[1] + b1v[1], 0.f);
                __half2 up2 = __floats2half2_rn(u0, u1);
                unsigned uv = *(unsigned*)&up2;
                xwrite4(u2w + (size_t)(slot * 64 + bg) * 256 + (jA >> 1), uv, slowm);
                u2f[((size_t)t * 64 + bg) * 256 + (jA >> 1)] = uv;   // plain: epilogue-only
            }
        }
        ++bno; if (tbar(sy, team, bno, slowm, s_bc)) return;
    }
}

// ---------------- E0: cbp = cb_w2 @ u_t + cb_b2 for all (b,t) ----------------
__global__ __launch_bounds__(256) void k_pred_all(
    const char* __restrict__ ws,
    const float* __restrict__ cb_b2,
    float* __restrict__ cbp)           // [64,1024,64]
{
    const uint4* u4 = (const uint4*)(ws + OFF_U2F);
    const uint4* w4 = (const uint4*)(ws + OFF_WC2);
    const int tid = threadIdx.x;
    const int rr = tid >> 4, dd = tid & 15;
    const int r = blockIdx.x * 16 + rr;
    const int b = r >> 10, t = r & 1023;
    const uint4* urow = u4 + ((size_t)t * 64 + b) * 64;
    float acc[4] = {0.f, 0.f, 0.f, 0.f};
    for (int jc = 0; jc < 64; jc += 2) {
        V16 ua0, ua1;
        ua0.u = urow[jc]; ua1.u = urow[jc + 1];
#pragma unroll
        for (int m = 0; m < 4; ++m) {
            int d = dd + m * 16;
            V16 w0, w1;
            w0.u = w4[(size_t)d * 64 + jc];
            w1.u = w4[(size_t)d * 64 + jc + 1];
            __half2 s = __hmul2(w0.h[0], ua0.h[0]);
            s = __hfma2(w0.h[1], ua0.h[1], s);
            s = __hfma2(w0.h[2], ua0.h[2], s);
            s = __hfma2(w0.h[3], ua0.h[3], s);
            s = __hfma2(w1.h[0], ua1.h[0], s);
            s = __hfma2(w1.h[1], ua1.h[1], s);
            s = __hfma2(w1.h[2], ua1.h[2], s);
            s = __hfma2(w1.h[3], ua1.h[3], s);
            float2 f = __half22float2(s);
            acc[m] += f.x + f.y;
        }
    }
#pragma unroll
    for (int m = 0; m < 4; ++m) {
        int d = dd + m * 16;
        cbp[((size_t)b * 1024 + t) * 64 + d] = acc[m] + cb_b2[d];
    }
}

// ---------------- E1: ca1 = relu(h @ fc_w.T + fc_b), IN PLACE (unchanged) ----------------
__global__ __launch_bounds__(256) void k_fc_inplace(
    float* __restrict__ hist,        // in: h rows, out: ca1 rows  [65536,512]
    const float* __restrict__ fc_w,  // [512,512]
    const float* __restrict__ fc_b)  // [512]
{
    __shared__ __align__(16) float s_a[16 * 516];
    const int tid = threadIdx.x;
    const int r = tid & 15;
    const int jset = tid >> 4;
    const int row0 = blockIdx.x * 16;

    for (int i = tid; i < 2048; i += 256) {
        int rr = i >> 7, f = i & 127;
        float4 v = *(const float4*)(hist + (size_t)(row0 + rr) * H_ + f * 4);
        *(float4*)(s_a + rr * 516 + f * 4) = v;
    }
    __syncthreads();

    float acc[32];
#pragma unroll
    for (int jj = 0; jj < 32; ++jj) acc[jj] = 0.f;

    const float4* arow = (const float4*)(s_a + r * 516);
    for (int k4 = 0; k4 < 128; ++k4) {
        float4 a = arow[k4];
#pragma unroll
        for (int jj = 0; jj < 32; ++jj) {
            int j = jset + (jj << 4);
            float4 w = *(const float4*)(fc_w + (size_t)j * 512 + k4 * 4);
            acc[jj] += a.x * w.x + a.y * w.y + a.z * w.z + a.w * w.w;
        }
    }

    float* crow = hist + (size_t)(row0 + r) * H_;
#pragma unroll
    for (int jj = 0; jj < 32; ++jj) {
        int j = jset + (jj << 4);
        float v = acc[jj] + fc_b[j];
        crow[j] = fmaxf(v, 0.f);
    }
}

// ---------------- E3: q = ca1 @ out_w.T + out_b (unchanged) ----------------
__global__ __launch_bounds__(256) void k_q(
    const float* __restrict__ ca1,   // [65536,512]
    const float* __restrict__ out_w, // [16,512]
    const float* __restrict__ out_b, // [16]
    float* __restrict__ q)           // [65536,16]
{
    __shared__ __align__(16) float s_a[16 * 516];
    __shared__ __align__(16) float s_w[16 * 516];
    const int tid = threadIdx.x;
    const int r = tid >> 4;
    const int a_ = tid & 15;
    const int row0 = blockIdx.x * 16;

    for (int i = tid; i < 2048; i += 256) {
        int rr = i >> 7, f = i & 127;
        float4 v = *(const float4*)(ca1 + (size_t)(row0 + rr) * H_ + f * 4);
        *(float4*)(s_a + rr * 516 + f * 4) = v;
    }
    for (int i = tid; i < 2048; i += 256) {
        int rr = i >> 7, f = i & 127;
        float4 v = *(const float4*)(out_w + (size_t)rr * 512 + f * 4);
        *(float4*)(s_w + rr * 516 + f * 4) = v;
    }
    __syncthreads();

    const float4* arow = (const float4*)(s_a + r * 516);
    const float4* wrow = (const float4*)(s_w + a_ * 516);
    float acc = 0.f;
#pragma unroll 8
    for (int k4 = 0; k4 < 128; ++k4) {
        float4 a = arow[k4];
        float4 w = wrow[k4];
        acc += a.x * w.x + a.y * w.y + a.z * w.z + a.w * w.w;
    }
    q[(size_t)(row0 + r) * A_ + a_] = acc + out_b[a_];
}

// ---------------- host ----------------
extern "C" void kernel_launch(void* const* d_in, const int* in_sizes, int n_in,
                              void* d_out, int out_size, void* d_ws, size_t ws_size,
                              hipStream_t stream) {
    const float* x     = (const float*)d_in[0];
    const float* W_ih  = (const float*)d_in[1];
    const float* W_hh  = (const float*)d_in[2];
    const float* b_ih  = (const float*)d_in[3];
    const float* b_hh  = (const float*)d_in[4];
    const float* fc_w  = (const float*)d_in[5];
    const float* fc_b  = (const float*)d_in[6];
    const float* out_w = (const float*)d_in[7];
    const float* out_b = (const float*)d_in[8];
    const float* cb_w1 = (const float*)d_in[9];
    const float* cb_b1 = (const float*)d_in[10];
    const float* cb_w2 = (const float*)d_in[11];
    const float* cb_b2 = (const float*)d_in[12];

    float* q_out  = (float*)d_out;                     // [64,1024,16]
    float* cbp    = q_out + (size_t)B_ * S_ * A_;      // [64,1024,64]
    float* hidden = cbp + (size_t)B_ * S_ * D_;        // [1,64,512]
    float* ca1    = hidden + (size_t)B_ * H_;          // [64,1024,512] (h-history then ca1)

    char* ws = (char*)d_ws;                            // ~68 MB used

    k_convert<<<590, 256, 0, stream>>>(W_ih, W_hh, cb_w1, cb_w2, cb_b2, ws);
    k_wf<<<384, 256, 0, stream>>>(W_ih, cb_w2, ws);
    k_recur<<<NWG, THR, 0, stream>>>(ws, x, b_ih, b_hh, cb_b1, ca1, hidden);
    k_pred_all<<<4096, 256, 0, stream>>>(ws, cb_b2, cbp);
    k_fc_inplace<<<4096, 256, 0, stream>>>(ca1, fc_w, fc_b);
    k_q<<<4096, 256, 0, stream>>>(ca1, out_w, out_b, q_out);
}